// Round 3
// baseline (217.992 us; speedup 1.0000x reference)
//
#include <hip/hip_runtime.h>

#define N_NODES 100000
#define N_EDGES 1600000
#define HD 128
#define SLOPE 0.2f
#define NBLK 391            // ceil(N_NODES/256)
#define GB 782              // gemm v-blocks: ceil(N_NODES/128)
#define EB2 3125            // edge v-blocks of 512: N_EDGES/512
#define PB 1024             // persistent blocks for K1 (4/CU x 256 CU)
#define CAP 32              // adjacency bucket capacity (P(deg>32) ~ 1e-19)

typedef __attribute__((ext_vector_type(8))) short bf16x8;
typedef __attribute__((ext_vector_type(4))) float f32x4;

__device__ __forceinline__ unsigned short f2bf(float f) {
    union { float f; unsigned u; } v; v.f = f;
    const unsigned u = v.u + 0x7FFFu + ((v.u >> 16) & 1u);   // RNE
    return (unsigned short)(u >> 16);
}
__device__ __forceinline__ unsigned pack2(float lo, float hi) {
    return (unsigned)f2bf(lo) | ((unsigned)f2bf(hi) << 16);
}
__device__ __forceinline__ float bf2f(unsigned u16) {
    union { unsigned u; float f; } v; v.u = u16 << 16; return v.f;
}

// ---------------------------------------------------------------------------
// K0: zero deg + node-active bitmask + W1^T bf16 convert.
// ---------------------------------------------------------------------------
__global__ __launch_bounds__(256) void k0_zero(
    const int* __restrict__ nt, const float* __restrict__ W1,
    int* __restrict__ deg, unsigned* __restrict__ umask,
    unsigned short* __restrict__ W1bfT)
{
    const int i = blockIdx.x * 256 + threadIdx.x;
    bool act = false;
    if (i < N_NODES) { deg[i] = 0; act = (nt[i] == 0); }
    const unsigned long long bal = __ballot(act);
    const int lane = threadIdx.x & 63;
    if (lane == 0)       umask[i >> 5] = (unsigned)bal;
    else if (lane == 32) umask[i >> 5] = (unsigned)(bal >> 32);
    if (i < HD * HD) {
        const int n = i >> 7, k = i & 127;
        W1bfT[n * HD + k] = f2bf(W1[k * HD + n]);
    }
}

// ---------------------------------------------------------------------------
// K1: persistent-grid fused gemm1 + edge bucket-build.
// PB=1024 blocks (exactly 4/CU with 32KB LDS). Block b does GEMM v-tile b
// (if b < GB), then grid-strides over edge v-chunks. This puts edge work on
// ALL block slots instead of funneling 3125 edge blocks through the ~242
// slots the GEMM leaves free (the round-2 43us tail).
// ---------------------------------------------------------------------------
__global__ __launch_bounds__(512, 8) void k1_gemm_edge(
    const int* __restrict__ h,
    const float* __restrict__ emb,
    const unsigned short* __restrict__ W1bfT,
    const float* __restrict__ a_src1,
    const float* __restrict__ a_dst1,
    unsigned short* __restrict__ xp1,
    float* __restrict__ es1,
    float* __restrict__ ed1,
    float* __restrict__ denom1,
    const int* __restrict__ ei,
    const unsigned* __restrict__ umask,
    int* __restrict__ deg,
    int* __restrict__ adj)
{
    __shared__ unsigned short Wlds[HD * HD];   // 32 KB; reused as store-stage
    const int tid = threadIdx.x;

    for (int vb = blockIdx.x; vb < GB + EB2; vb += PB) {
        if (vb >= GB) {
            // ------------------------- edge chunk -------------------------
            const int e = (vb - GB) * 512 + tid;
            const int src = ei[e];
            const int dst = ei[N_EDGES + e];
            const bool active =
                (((umask[src >> 5] >> (src & 31)) & (umask[dst >> 5] >> (dst & 31))) & 1u) != 0u;
            if (active) {
                const int slot = atomicAdd(deg + dst, 1);
                if (slot < CAP) adj[(size_t)dst * CAP + slot] = src;
            }
            continue;
        }

        // ------------------------- gemm tile (vb < GB, runs once) ---------
        // stage W^T: thread t -> col n = t>>2, k-quarter (t&3)*32, swizzled
        {
            const int n  = tid >> 2;
            const int kq = (tid & 3) * 32;
            const unsigned short* src = W1bfT + n * HD + kq;
            #pragma unroll
            for (int j = 0; j < 4; ++j) {
                const int c = (kq >> 3) + j;               // 16B chunk index along k
                const int p = c ^ (n & 7);                 // swizzle
                *(bf16x8*)(Wlds + n * HD + p * 8) = *(const bf16x8*)(src + j * 8);
            }
        }

        const int w   = tid >> 6;                          // 0..7
        const int L   = tid & 63;
        const int lm  = L & 15;
        const int lg  = L >> 4;
        const int wrow0 = vb * 128 + w * 16;

        const int arow = wrow0 + lm;
        const int g = (arow < N_NODES) ? arow : (N_NODES - 1);
        const float* xrow = emb + (size_t)h[g] * HD;

        __syncthreads();

        f32x4 acc[8];
        #pragma unroll
        for (int ct = 0; ct < 8; ++ct) acc[ct] = (f32x4)0.f;

        #pragma unroll
        for (int ks = 0; ks < 4; ++ks) {
            const int k0 = ks * 32 + lg * 8;
            const float4 u = *(const float4*)(xrow + k0);
            const float4 v = *(const float4*)(xrow + k0 + 4);
            union { bf16x8 b; unsigned x[4]; } t;
            t.x[0] = pack2(u.x, u.y);
            t.x[1] = pack2(u.z, u.w);
            t.x[2] = pack2(v.x, v.y);
            t.x[3] = pack2(v.z, v.w);
            const bf16x8 af = t.b;

            const int c = k0 >> 3;
            const int p = (c ^ (lm & 7)) * 8;              // n&7 == lm&7 for frag reads
            #pragma unroll
            for (int ct = 0; ct < 8; ++ct) {
                const bf16x8 bfr = *(const bf16x8*)(Wlds + (ct * 16 + lm) * HD + p);
                acc[ct] = __builtin_amdgcn_mfma_f32_16x16x32_bf16(af, bfr, acc[ct], 0, 0, 0);
            }
        }

        // attention dots (C/D: col = lm, row-in-tile = lg*4+reg)
        float asv[8], adv[8];
        #pragma unroll
        for (int ct = 0; ct < 8; ++ct) {
            asv[ct] = a_src1[ct * 16 + lm];
            adv[ct] = a_dst1[ct * 16 + lm];
        }

        #pragma unroll
        for (int reg = 0; reg < 4; ++reg) {
            const int row = wrow0 + lg * 4 + reg;
            float s = 0.f, d = 0.f;
            #pragma unroll
            for (int ct = 0; ct < 8; ++ct) {
                s += acc[ct][reg] * asv[ct];
                d += acc[ct][reg] * adv[ct];
            }
            #pragma unroll
            for (int m = 1; m < 16; m <<= 1) {   // reduce over the 16 lm lanes
                s += __shfl_xor(s, m, 64);
                d += __shfl_xor(d, m, 64);
            }
            if (row < N_NODES && lm == 0) {
                const float sum = s + d;
                const float l = sum > 0.f ? sum : SLOPE * sum;
                es1[row] = s;
                ed1[row] = d;
                denom1[row] = __expf(l);
            }
        }

        // ---- coalesced xp1 store via LDS transpose stage (W is dead) ----
        __syncthreads();                       // everyone done reading Wlds
        unsigned short* slice = Wlds + w * 2048;   // 16 rows x 128 cols bf16
        #pragma unroll
        for (int ct = 0; ct < 8; ++ct)
            #pragma unroll
            for (int reg = 0; reg < 4; ++reg)
                slice[(lg * 4 + reg) * HD + ct * 16 + lm] = f2bf(acc[ct][reg]);
        #pragma unroll
        for (int rr = 0; rr < 4; ++rr) {
            const int rl = rr * 4 + lg;        // 0..15
            const int row = wrow0 + rl;
            if (row < N_NODES) {
                const bf16x8 vdat = *(const bf16x8*)(slice + rl * HD + lm * 8);
                *(bf16x8*)(xp1 + (size_t)row * HD + lm * 8) = vdat;
            }
        }
        // no barrier needed after: next loop iterations are edge chunks
        // (vb+PB >= GB always, since GB < PB), which never touch Wlds.
    }
}

// ---------------------------------------------------------------------------
// K2: gather layer 1, one wave per node. Neighbor indices + weights computed
// in PARALLEL across lanes (one gather + exp each), denominator wave-reduced
// up-front; then a 2-way unrolled row-gather loop (independent 256B loads).
// ---------------------------------------------------------------------------
__global__ __launch_bounds__(256) void k2_gather(
    const unsigned short* __restrict__ xp1, const float* __restrict__ denom1,
    const float* __restrict__ es1, const float* __restrict__ ed1,
    const int* __restrict__ deg, const int* __restrict__ adj,
    const float* __restrict__ b1, const float* __restrict__ W2,
    float* __restrict__ xp2)
{
    const int wid = threadIdx.x >> 6;
    const int lane = threadIdx.x & 63;
    const int i = blockIdx.x * 4 + wid;
    if (i >= N_NODES) return;

    const int dcount = min(deg[i], CAP);
    const float wself = denom1[i];
    const float edv   = ed1[i];
    const int* arow = adj + (size_t)i * CAP;

    // parallel neighbor metadata
    int nidx = 0; float nw = 0.f;
    if (lane < dcount) {
        nidx = arow[lane];
        const float lgt = es1[nidx] + edv;
        nw = __expf(lgt > 0.f ? lgt : SLOPE * lgt);
    }
    float dsum = nw;
    #pragma unroll
    for (int m = 32; m > 0; m >>= 1) dsum += __shfl_xor(dsum, m, 64);
    const float inv = 1.f / (wself + dsum);

    const unsigned pself = ((const unsigned*)(xp1 + (size_t)i * HD))[lane];
    float a0 = wself * bf2f(pself & 0xFFFFu);
    float a1 = wself * bf2f(pself >> 16);

    int j = 0;
    for (; j + 2 <= dcount; j += 2) {
        const int   s0 = __shfl(nidx, j, 64);
        const int   s1 = __shfl(nidx, j + 1, 64);
        const float w0 = __shfl(nw, j, 64);
        const float w1 = __shfl(nw, j + 1, 64);
        const unsigned p0 = ((const unsigned*)(xp1 + (size_t)s0 * HD))[lane];
        const unsigned p1 = ((const unsigned*)(xp1 + (size_t)s1 * HD))[lane];
        a0 += w0 * bf2f(p0 & 0xFFFFu) + w1 * bf2f(p1 & 0xFFFFu);
        a1 += w0 * bf2f(p0 >> 16)     + w1 * bf2f(p1 >> 16);
    }
    if (j < dcount) {
        const int   s0 = __shfl(nidx, j, 64);
        const float w0 = __shfl(nw, j, 64);
        const unsigned p0 = ((const unsigned*)(xp1 + (size_t)s0 * HD))[lane];
        a0 += w0 * bf2f(p0 & 0xFFFFu);
        a1 += w0 * bf2f(p0 >> 16);
    }

    const float o0 = fmaxf(a0 * inv + b1[2 * lane],     0.f);
    const float o1 = fmaxf(a1 * inv + b1[2 * lane + 1], 0.f);

    float part = o0 * W2[2 * lane] + o1 * W2[2 * lane + 1];
    #pragma unroll
    for (int off = 32; off > 0; off >>= 1) part += __shfl_down(part, off, 64);
    if (lane == 0) xp2[i] = part;
}

// ---------------------------------------------------------------------------
// K3: layer 2 over scalars (one thread per node), 2-way unrolled with int2
// adjacency loads -> two independent load+exp chains per iteration.
// ---------------------------------------------------------------------------
__global__ __launch_bounds__(256) void k3_final(
    const float* __restrict__ xp2, const int* __restrict__ deg,
    const int* __restrict__ adj,
    const float* __restrict__ a_src2, const float* __restrict__ a_dst2,
    const float* __restrict__ b2, float* __restrict__ out)
{
    const int i = blockIdx.x * 256 + threadIdx.x;
    if (i >= N_NODES) return;

    const float as = a_src2[0], ad = a_dst2[0];
    const float xi = xp2[i];
    const float adxi = ad * xi;
    const float s0 = (as + ad) * xi;
    const float l0 = s0 > 0.f ? s0 : SLOPE * s0;
    const float wself = __expf(l0);

    float denom = wself, num = wself * xi;
    const int dcount = min(deg[i], CAP);
    const int* arow = adj + (size_t)i * CAP;

    int j = 0;
    for (; j + 2 <= dcount; j += 2) {
        const int2 ss = *(const int2*)(arow + j);
        const float x0 = xp2[ss.x];
        const float x1 = xp2[ss.y];
        float l0e = as * x0 + adxi; l0e = l0e > 0.f ? l0e : SLOPE * l0e;
        float l1e = as * x1 + adxi; l1e = l1e > 0.f ? l1e : SLOPE * l1e;
        const float w0 = __expf(l0e);
        const float w1 = __expf(l1e);
        denom += w0 + w1;
        num   += w0 * x0 + w1 * x1;
    }
    if (j < dcount) {
        const float x0 = xp2[arow[j]];
        float l0e = as * x0 + adxi; l0e = l0e > 0.f ? l0e : SLOPE * l0e;
        const float w0 = __expf(l0e);
        denom += w0;
        num   += w0 * x0;
    }
    out[i] = num / denom + b2[0];
}

extern "C" void kernel_launch(void* const* d_in, const int* in_sizes, int n_in,
                              void* d_out, int out_size, void* d_ws, size_t ws_size,
                              hipStream_t stream)
{
    const int* h   = (const int*)d_in[0];
    const int* ei  = (const int*)d_in[1];
    const int* nt  = (const int*)d_in[2];
    const float* emb    = (const float*)d_in[3];
    const float* W1     = (const float*)d_in[4];
    const float* a_src1 = (const float*)d_in[5];
    const float* a_dst1 = (const float*)d_in[6];
    const float* b1     = (const float*)d_in[7];
    const float* W2     = (const float*)d_in[8];
    const float* a_src2 = (const float*)d_in[9];
    const float* a_dst2 = (const float*)d_in[10];
    const float* b2     = (const float*)d_in[11];
    float* out = (float*)d_out;

    char* ws = (char*)d_ws;
    size_t off = 0;
    unsigned short* xp1 = (unsigned short*)(ws + off); off += (size_t)N_NODES * HD * sizeof(unsigned short);
    float* es1    = (float*)(ws + off); off += (size_t)N_NODES * sizeof(float);
    float* ed1    = (float*)(ws + off); off += (size_t)N_NODES * sizeof(float);
    float* denom1 = (float*)(ws + off); off += (size_t)N_NODES * sizeof(float);
    float* xp2    = (float*)(ws + off); off += (size_t)N_NODES * sizeof(float);
    int*   deg    = (int*)(ws + off);   off += (size_t)N_NODES * sizeof(int);
    unsigned* umask = (unsigned*)(ws + off); off += 3200 * sizeof(unsigned);
    unsigned short* W1bfT = (unsigned short*)(ws + off); off += (size_t)HD * HD * sizeof(unsigned short);
    off = (off + 255) & ~(size_t)255;
    int*   adj    = (int*)(ws + off);   off += (size_t)N_NODES * CAP * sizeof(int);

    k0_zero<<<NBLK, 256, 0, stream>>>(nt, W1, deg, umask, W1bfT);
    k1_gemm_edge<<<PB, 512, 0, stream>>>(
        h, emb, W1bfT, a_src1, a_dst1, xp1, es1, ed1, denom1,
        ei, umask, deg, adj);
    k2_gather<<<(N_NODES + 3) / 4, 256, 0, stream>>>(
        xp1, denom1, es1, ed1, deg, adj, b1, W2, xp2);
    k3_final<<<NBLK, 256, 0, stream>>>(
        xp2, deg, adj, a_src2, a_dst2, b2, out);
}

// Round 4
// 180.468 us; speedup vs baseline: 1.2079x; 1.2079x over previous
//
#include <hip/hip_runtime.h>

#define N_NODES 100000
#define N_EDGES 1600000
#define HD 128
#define SLOPE 0.2f
#define NBLK 391            // ceil(N_NODES/256)
#define GB 782              // gemm blocks: ceil(N_NODES/128)
#define EB2 3125            // edge blocks of 512: N_EDGES/512
#define CAP 32              // adjacency bucket capacity (P(deg>32) ~ 1e-19)

typedef __attribute__((ext_vector_type(8))) short bf16x8;
typedef __attribute__((ext_vector_type(4))) float f32x4;

__device__ __forceinline__ unsigned short f2bf(float f) {
    union { float f; unsigned u; } v; v.f = f;
    const unsigned u = v.u + 0x7FFFu + ((v.u >> 16) & 1u);   // RNE
    return (unsigned short)(u >> 16);
}
__device__ __forceinline__ unsigned pack2(float lo, float hi) {
    return (unsigned)f2bf(lo) | ((unsigned)f2bf(hi) << 16);
}
__device__ __forceinline__ float bf2f(unsigned u16) {
    union { unsigned u; float f; } v; v.u = u16 << 16; return v.f;
}

// ---------------------------------------------------------------------------
// K0: zero deg + node-active bitmask + W1^T bf16 convert.
// ---------------------------------------------------------------------------
__global__ __launch_bounds__(256) void k0_zero(
    const int* __restrict__ nt, const float* __restrict__ W1,
    int* __restrict__ deg, unsigned* __restrict__ umask,
    unsigned short* __restrict__ W1bfT)
{
    const int i = blockIdx.x * 256 + threadIdx.x;
    bool act = false;
    if (i < N_NODES) { deg[i] = 0; act = (nt[i] == 0); }
    const unsigned long long bal = __ballot(act);
    const int lane = threadIdx.x & 63;
    if (lane == 0)       umask[i >> 5] = (unsigned)bal;
    else if (lane == 32) umask[i >> 5] = (unsigned)(bal >> 32);
    if (i < HD * HD) {
        const int n = i >> 7, k = i & 127;
        W1bfT[n * HD + k] = f2bf(W1[k * HD + n]);
    }
}

// ---------------------------------------------------------------------------
// K1: fused edge bucket-build + gemm1 (ROUND-2 structure, reverted from the
// round-3 persistent grid which amplified traffic 70->175 MB).
// Change vs round-2: EDGE BLOCKS FIRST (blocks [0,EB2)) so the short edge
// bursts drain at full machine width (~5us) before the long GEMM blocks
// (blocks [EB2, EB2+GB)) occupy the slots — removes the 242-slot edge funnel.
// ---------------------------------------------------------------------------
__global__ __launch_bounds__(512, 8) void k1_gemm_edge(
    const int* __restrict__ h,
    const float* __restrict__ emb,
    const unsigned short* __restrict__ W1bfT,
    const float* __restrict__ a_src1,
    const float* __restrict__ a_dst1,
    unsigned short* __restrict__ xp1,
    float* __restrict__ es1,
    float* __restrict__ ed1,
    float* __restrict__ denom1,
    const int* __restrict__ ei,
    const unsigned* __restrict__ umask,
    int* __restrict__ deg,
    int* __restrict__ adj)
{
    __shared__ unsigned short Wlds[HD * HD];   // 32 KB (edge blocks don't touch)
    const int tid = threadIdx.x;

    if (blockIdx.x < EB2) {
        // ------------------------- edge pass -------------------------
        const int e = blockIdx.x * 512 + tid;
        const int src = ei[e];
        const int dst = ei[N_EDGES + e];
        const bool active =
            (((umask[src >> 5] >> (src & 31)) & (umask[dst >> 5] >> (dst & 31))) & 1u) != 0u;
        if (active) {
            const int slot = atomicAdd(deg + dst, 1);
            if (slot < CAP) adj[(size_t)dst * CAP + slot] = src;
        }
        return;
    }
    const int vb = blockIdx.x - EB2;           // gemm tile index 0..GB-1

    // ------------------------- gemm path -------------------------
    // stage W^T: thread t -> col n = t>>2, k-quarter (t&3)*32, swizzled
    {
        const int n  = tid >> 2;
        const int kq = (tid & 3) * 32;
        const unsigned short* src = W1bfT + n * HD + kq;
        #pragma unroll
        for (int j = 0; j < 4; ++j) {
            const int c = (kq >> 3) + j;               // 16B chunk index along k
            const int p = c ^ (n & 7);                 // swizzle
            *(bf16x8*)(Wlds + n * HD + p * 8) = *(const bf16x8*)(src + j * 8);
        }
    }

    const int w   = tid >> 6;                          // 0..7
    const int L   = tid & 63;
    const int lm  = L & 15;
    const int lg  = L >> 4;
    const int wrow0 = vb * 128 + w * 16;

    const int arow = wrow0 + lm;
    const int g = (arow < N_NODES) ? arow : (N_NODES - 1);
    const float* xrow = emb + (size_t)h[g] * HD;

    __syncthreads();

    f32x4 acc[8];
    #pragma unroll
    for (int ct = 0; ct < 8; ++ct) acc[ct] = (f32x4)0.f;

    #pragma unroll
    for (int ks = 0; ks < 4; ++ks) {
        const int k0 = ks * 32 + lg * 8;
        const float4 u = *(const float4*)(xrow + k0);
        const float4 v = *(const float4*)(xrow + k0 + 4);
        union { bf16x8 b; unsigned x[4]; } t;
        t.x[0] = pack2(u.x, u.y);
        t.x[1] = pack2(u.z, u.w);
        t.x[2] = pack2(v.x, v.y);
        t.x[3] = pack2(v.z, v.w);
        const bf16x8 af = t.b;

        const int c = k0 >> 3;
        const int p = (c ^ (lm & 7)) * 8;              // n&7 == lm&7 for frag reads
        #pragma unroll
        for (int ct = 0; ct < 8; ++ct) {
            const bf16x8 bfr = *(const bf16x8*)(Wlds + (ct * 16 + lm) * HD + p);
            acc[ct] = __builtin_amdgcn_mfma_f32_16x16x32_bf16(af, bfr, acc[ct], 0, 0, 0);
        }
    }

    // attention dots + store (C/D: col = lm, row-in-tile = lg*4+reg)
    float asv[8], adv[8];
    #pragma unroll
    for (int ct = 0; ct < 8; ++ct) {
        asv[ct] = a_src1[ct * 16 + lm];
        adv[ct] = a_dst1[ct * 16 + lm];
    }

    #pragma unroll
    for (int reg = 0; reg < 4; ++reg) {
        const int row = wrow0 + lg * 4 + reg;
        float s = 0.f, d = 0.f;
        #pragma unroll
        for (int ct = 0; ct < 8; ++ct) {
            s += acc[ct][reg] * asv[ct];
            d += acc[ct][reg] * adv[ct];
        }
        #pragma unroll
        for (int m = 1; m < 16; m <<= 1) {   // reduce over the 16 lm lanes
            s += __shfl_xor(s, m, 64);
            d += __shfl_xor(d, m, 64);
        }
        if (row < N_NODES) {
            unsigned short* dst = xp1 + (size_t)row * HD;
            #pragma unroll
            for (int ct = 0; ct < 8; ++ct)
                dst[ct * 16 + lm] = f2bf(acc[ct][reg]);
            if (lm == 0) {
                const float sum = s + d;
                const float l = sum > 0.f ? sum : SLOPE * sum;
                es1[row] = s;
                ed1[row] = d;
                denom1[row] = __expf(l);
            }
        }
    }
}

// ---------------------------------------------------------------------------
// K2: gather layer 1, one wave per node, with DEG-0 FAST PATH (~67% of
// nodes): softmax collapses to alpha_self=1 -> out = relu(xp1_row + b1);
// skips denom1/ed1/es1/adj loads, exp, and reductions entirely. Deg>0 path:
// lane-parallel weight precompute + 2-way unrolled row-gather.
// ---------------------------------------------------------------------------
__global__ __launch_bounds__(256) void k2_gather(
    const unsigned short* __restrict__ xp1, const float* __restrict__ denom1,
    const float* __restrict__ es1, const float* __restrict__ ed1,
    const int* __restrict__ deg, const int* __restrict__ adj,
    const float* __restrict__ b1, const float* __restrict__ W2,
    float* __restrict__ xp2)
{
    const int wid = threadIdx.x >> 6;
    const int lane = threadIdx.x & 63;
    const int i = blockIdx.x * 4 + wid;
    if (i >= N_NODES) return;

    const int dcount = min(deg[i], CAP);

    const unsigned pself = ((const unsigned*)(xp1 + (size_t)i * HD))[lane];
    float a0 = bf2f(pself & 0xFFFFu);
    float a1 = bf2f(pself >> 16);

    if (dcount > 0) {
        const float wself = denom1[i];
        const float edv   = ed1[i];
        const int* arow = adj + (size_t)i * CAP;

        // parallel neighbor metadata (one gather + exp per lane)
        int nidx = 0; float nw = 0.f;
        if (lane < dcount) {
            nidx = arow[lane];
            const float lgt = es1[nidx] + edv;
            nw = __expf(lgt > 0.f ? lgt : SLOPE * lgt);
        }
        float dsum = nw;
        #pragma unroll
        for (int m = 32; m > 0; m >>= 1) dsum += __shfl_xor(dsum, m, 64);
        const float inv = 1.f / (wself + dsum);

        a0 *= wself;
        a1 *= wself;

        int j = 0;
        for (; j + 2 <= dcount; j += 2) {
            const int   s0 = __shfl(nidx, j, 64);
            const int   s1 = __shfl(nidx, j + 1, 64);
            const float w0 = __shfl(nw, j, 64);
            const float w1 = __shfl(nw, j + 1, 64);
            const unsigned p0 = ((const unsigned*)(xp1 + (size_t)s0 * HD))[lane];
            const unsigned p1 = ((const unsigned*)(xp1 + (size_t)s1 * HD))[lane];
            a0 += w0 * bf2f(p0 & 0xFFFFu) + w1 * bf2f(p1 & 0xFFFFu);
            a1 += w0 * bf2f(p0 >> 16)     + w1 * bf2f(p1 >> 16);
        }
        if (j < dcount) {
            const int   s0 = __shfl(nidx, j, 64);
            const float w0 = __shfl(nw, j, 64);
            const unsigned p0 = ((const unsigned*)(xp1 + (size_t)s0 * HD))[lane];
            a0 += w0 * bf2f(p0 & 0xFFFFu);
            a1 += w0 * bf2f(p0 >> 16);
        }
        a0 *= inv;
        a1 *= inv;
    }
    // deg==0: denom == wself, numerator == wself * x  ->  a = x (already)

    const float o0 = fmaxf(a0 + b1[2 * lane],     0.f);
    const float o1 = fmaxf(a1 + b1[2 * lane + 1], 0.f);

    float part = o0 * W2[2 * lane] + o1 * W2[2 * lane + 1];
    #pragma unroll
    for (int off = 32; off > 0; off >>= 1) part += __shfl_down(part, off, 64);
    if (lane == 0) xp2[i] = part;
}

// ---------------------------------------------------------------------------
// K3: layer 2 over scalars (one thread per node) with deg-0 fast path
// (out = xi + b2); deg>0: 2-way unrolled int2 adjacency + independent exps.
// ---------------------------------------------------------------------------
__global__ __launch_bounds__(256) void k3_final(
    const float* __restrict__ xp2, const int* __restrict__ deg,
    const int* __restrict__ adj,
    const float* __restrict__ a_src2, const float* __restrict__ a_dst2,
    const float* __restrict__ b2, float* __restrict__ out)
{
    const int i = blockIdx.x * 256 + threadIdx.x;
    if (i >= N_NODES) return;

    const float xi = xp2[i];
    const int dcount = min(deg[i], CAP);
    if (dcount == 0) {                       // denom=wself, num=wself*xi
        out[i] = xi + b2[0];
        return;
    }

    const float as = a_src2[0], ad = a_dst2[0];
    const float adxi = ad * xi;
    const float s0 = (as + ad) * xi;
    const float l0 = s0 > 0.f ? s0 : SLOPE * s0;
    const float wself = __expf(l0);

    float denom = wself, num = wself * xi;
    const int* arow = adj + (size_t)i * CAP;

    int j = 0;
    for (; j + 2 <= dcount; j += 2) {
        const int2 ss = *(const int2*)(arow + j);
        const float x0 = xp2[ss.x];
        const float x1 = xp2[ss.y];
        float l0e = as * x0 + adxi; l0e = l0e > 0.f ? l0e : SLOPE * l0e;
        float l1e = as * x1 + adxi; l1e = l1e > 0.f ? l1e : SLOPE * l1e;
        const float w0 = __expf(l0e);
        const float w1 = __expf(l1e);
        denom += w0 + w1;
        num   += w0 * x0 + w1 * x1;
    }
    if (j < dcount) {
        const float x0 = xp2[arow[j]];
        float l0e = as * x0 + adxi; l0e = l0e > 0.f ? l0e : SLOPE * l0e;
        const float w0 = __expf(l0e);
        denom += w0;
        num   += w0 * x0;
    }
    out[i] = num / denom + b2[0];
}

extern "C" void kernel_launch(void* const* d_in, const int* in_sizes, int n_in,
                              void* d_out, int out_size, void* d_ws, size_t ws_size,
                              hipStream_t stream)
{
    const int* h   = (const int*)d_in[0];
    const int* ei  = (const int*)d_in[1];
    const int* nt  = (const int*)d_in[2];
    const float* emb    = (const float*)d_in[3];
    const float* W1     = (const float*)d_in[4];
    const float* a_src1 = (const float*)d_in[5];
    const float* a_dst1 = (const float*)d_in[6];
    const float* b1     = (const float*)d_in[7];
    const float* W2     = (const float*)d_in[8];
    const float* a_src2 = (const float*)d_in[9];
    const float* a_dst2 = (const float*)d_in[10];
    const float* b2     = (const float*)d_in[11];
    float* out = (float*)d_out;

    char* ws = (char*)d_ws;
    size_t off = 0;
    unsigned short* xp1 = (unsigned short*)(ws + off); off += (size_t)N_NODES * HD * sizeof(unsigned short);
    float* es1    = (float*)(ws + off); off += (size_t)N_NODES * sizeof(float);
    float* ed1    = (float*)(ws + off); off += (size_t)N_NODES * sizeof(float);
    float* denom1 = (float*)(ws + off); off += (size_t)N_NODES * sizeof(float);
    float* xp2    = (float*)(ws + off); off += (size_t)N_NODES * sizeof(float);
    int*   deg    = (int*)(ws + off);   off += (size_t)N_NODES * sizeof(int);
    unsigned* umask = (unsigned*)(ws + off); off += 3200 * sizeof(unsigned);
    unsigned short* W1bfT = (unsigned short*)(ws + off); off += (size_t)HD * HD * sizeof(unsigned short);
    off = (off + 255) & ~(size_t)255;
    int*   adj    = (int*)(ws + off);   off += (size_t)N_NODES * CAP * sizeof(int);

    k0_zero<<<NBLK, 256, 0, stream>>>(nt, W1, deg, umask, W1bfT);
    k1_gemm_edge<<<EB2 + GB, 512, 0, stream>>>(
        h, emb, W1bfT, a_src1, a_dst1, xp1, es1, ed1, denom1,
        ei, umask, deg, adj);
    k2_gather<<<(N_NODES + 3) / 4, 256, 0, stream>>>(
        xp1, denom1, es1, ed1, deg, adj, b1, W2, xp2);
    k3_final<<<NBLK, 256, 0, stream>>>(
        xp2, deg, adj, a_src2, a_dst2, b2, out);
}

// Round 5
// 178.212 us; speedup vs baseline: 1.2232x; 1.0127x over previous
//
#include <hip/hip_runtime.h>

#define N_NODES 100000
#define N_EDGES 1600000
#define HD 128
#define SLOPE 0.2f
#define NBLK 391            // ceil(N_NODES/256)
#define GB 782              // gemm blocks: ceil(N_NODES/128)
#define EB3 1563            // edge blocks: ceil(N_EDGES/2/512), 2 edges/thread
#define CAP 32              // adjacency bucket capacity (P(deg>32) ~ 1e-19)
#define SLICE_LD 136        // padded LDS stage stride (shorts): 4-way ds_write

typedef __attribute__((ext_vector_type(8))) short bf16x8;
typedef __attribute__((ext_vector_type(4))) float f32x4;

__device__ __forceinline__ unsigned short f2bf(float f) {
    union { float f; unsigned u; } v; v.f = f;
    const unsigned u = v.u + 0x7FFFu + ((v.u >> 16) & 1u);   // RNE
    return (unsigned short)(u >> 16);
}
__device__ __forceinline__ unsigned pack2(float lo, float hi) {
    return (unsigned)f2bf(lo) | ((unsigned)f2bf(hi) << 16);
}
__device__ __forceinline__ float bf2f(unsigned u16) {
    union { unsigned u; float f; } v; v.u = u16 << 16; return v.f;
}

// ---------------------------------------------------------------------------
// K0: zero deg + node-active bitmask + W1^T bf16 convert.
// ---------------------------------------------------------------------------
__global__ __launch_bounds__(256) void k0_zero(
    const int* __restrict__ nt, const float* __restrict__ W1,
    int* __restrict__ deg, unsigned* __restrict__ umask,
    unsigned short* __restrict__ W1bfT)
{
    const int i = blockIdx.x * 256 + threadIdx.x;
    bool act = false;
    if (i < N_NODES) { deg[i] = 0; act = (nt[i] == 0); }
    const unsigned long long bal = __ballot(act);
    const int lane = threadIdx.x & 63;
    if (lane == 0)       umask[i >> 5] = (unsigned)bal;
    else if (lane == 32) umask[i >> 5] = (unsigned)(bal >> 32);
    if (i < HD * HD) {
        const int n = i >> 7, k = i & 127;
        W1bfT[n * HD + k] = f2bf(W1[k * HD + n]);
    }
}

// ---------------------------------------------------------------------------
// K1a: edge bucket-build, SPLIT OUT for per-phase counters. 2 edges/thread
// via int2 loads (halves wave count, 2 independent atomic chains per thread).
// ---------------------------------------------------------------------------
__global__ __launch_bounds__(512) void k1a_edge(
    const int* __restrict__ ei, const unsigned* __restrict__ umask,
    int* __restrict__ deg, int* __restrict__ adj)
{
    const int t = blockIdx.x * 512 + threadIdx.x;
    const int e0 = t * 2;
    if (e0 >= N_EDGES) return;
    const int2 s2 = *(const int2*)(ei + e0);
    const int2 d2 = *(const int2*)(ei + N_EDGES + e0);
    const bool a0 =
        (((umask[s2.x >> 5] >> (s2.x & 31)) & (umask[d2.x >> 5] >> (d2.x & 31))) & 1u) != 0u;
    const bool a1 =
        (((umask[s2.y >> 5] >> (s2.y & 31)) & (umask[d2.y >> 5] >> (d2.y & 31))) & 1u) != 0u;
    if (a0) {
        const int sl = atomicAdd(deg + d2.x, 1);
        if (sl < CAP) adj[(size_t)d2.x * CAP + sl] = s2.x;
    }
    if (a1) {
        const int sl = atomicAdd(deg + d2.y, 1);
        if (sl < CAP) adj[(size_t)d2.y * CAP + sl] = s2.y;
    }
}

// ---------------------------------------------------------------------------
// K1b: gemm1 (xp1 = emb[h] @ W1, bf16 MFMA), SPLIT OUT. Epilogue now stages
// the 16x128 wave tile in LDS (Wlds reused, padded stride 136) and stores
// xp1 as coalesced bf16x8 — replaces 128 scattered 2B stores per wave.
// ---------------------------------------------------------------------------
__global__ __launch_bounds__(512, 8) void k1b_gemm(
    const int* __restrict__ h,
    const float* __restrict__ emb,
    const unsigned short* __restrict__ W1bfT,
    const float* __restrict__ a_src1,
    const float* __restrict__ a_dst1,
    unsigned short* __restrict__ xp1,
    float* __restrict__ es1,
    float* __restrict__ ed1,
    float* __restrict__ denom1)
{
    __shared__ unsigned short Wlds[8 * 16 * SLICE_LD];   // 34 KB >= 16384 for W
    const int tid = threadIdx.x;

    // stage W^T: thread t -> col n = t>>2, k-quarter (t&3)*32, swizzled
    {
        const int n  = tid >> 2;
        const int kq = (tid & 3) * 32;
        const unsigned short* src = W1bfT + n * HD + kq;
        #pragma unroll
        for (int j = 0; j < 4; ++j) {
            const int c = (kq >> 3) + j;               // 16B chunk index along k
            const int p = c ^ (n & 7);                 // swizzle
            *(bf16x8*)(Wlds + n * HD + p * 8) = *(const bf16x8*)(src + j * 8);
        }
    }

    const int w   = tid >> 6;                          // 0..7
    const int L   = tid & 63;
    const int lm  = L & 15;
    const int lg  = L >> 4;
    const int wrow0 = blockIdx.x * 128 + w * 16;

    const int arow = wrow0 + lm;
    const int g = (arow < N_NODES) ? arow : (N_NODES - 1);
    const float* xrow = emb + (size_t)h[g] * HD;

    __syncthreads();

    f32x4 acc[8];
    #pragma unroll
    for (int ct = 0; ct < 8; ++ct) acc[ct] = (f32x4)0.f;

    #pragma unroll
    for (int ks = 0; ks < 4; ++ks) {
        const int k0 = ks * 32 + lg * 8;
        const float4 u = *(const float4*)(xrow + k0);
        const float4 v = *(const float4*)(xrow + k0 + 4);
        union { bf16x8 b; unsigned x[4]; } t;
        t.x[0] = pack2(u.x, u.y);
        t.x[1] = pack2(u.z, u.w);
        t.x[2] = pack2(v.x, v.y);
        t.x[3] = pack2(v.z, v.w);
        const bf16x8 af = t.b;

        const int c = k0 >> 3;
        const int p = (c ^ (lm & 7)) * 8;              // n&7 == lm&7 for frag reads
        #pragma unroll
        for (int ct = 0; ct < 8; ++ct) {
            const bf16x8 bfr = *(const bf16x8*)(Wlds + (ct * 16 + lm) * HD + p);
            acc[ct] = __builtin_amdgcn_mfma_f32_16x16x32_bf16(af, bfr, acc[ct], 0, 0, 0);
        }
    }

    // attention dots (C/D: col = lm, row-in-tile = lg*4+reg)
    float asv[8], adv[8];
    #pragma unroll
    for (int ct = 0; ct < 8; ++ct) {
        asv[ct] = a_src1[ct * 16 + lm];
        adv[ct] = a_dst1[ct * 16 + lm];
    }

    #pragma unroll
    for (int reg = 0; reg < 4; ++reg) {
        const int row = wrow0 + lg * 4 + reg;
        float s = 0.f, d = 0.f;
        #pragma unroll
        for (int ct = 0; ct < 8; ++ct) {
            s += acc[ct][reg] * asv[ct];
            d += acc[ct][reg] * adv[ct];
        }
        #pragma unroll
        for (int m = 1; m < 16; m <<= 1) {   // reduce over the 16 lm lanes
            s += __shfl_xor(s, m, 64);
            d += __shfl_xor(d, m, 64);
        }
        if (row < N_NODES && lm == 0) {
            const float sum = s + d;
            const float l = sum > 0.f ? sum : SLOPE * sum;
            es1[row] = s;
            ed1[row] = d;
            denom1[row] = __expf(l);
        }
    }

    // ---- coalesced xp1 store via LDS transpose stage (W is dead) ----
    __syncthreads();                       // everyone done reading W from Wlds
    unsigned short* slice = Wlds + w * 16 * SLICE_LD;   // 16 rows, padded
    #pragma unroll
    for (int ct = 0; ct < 8; ++ct)
        #pragma unroll
        for (int reg = 0; reg < 4; ++reg)
            slice[(lg * 4 + reg) * SLICE_LD + ct * 16 + lm] = f2bf(acc[ct][reg]);
    __syncthreads();                       // order intra-wave LDS write->read
    #pragma unroll
    for (int rr = 0; rr < 4; ++rr) {
        const int rl = rr * 4 + lg;        // 0..15
        const int row = wrow0 + rl;
        if (row < N_NODES) {
            const bf16x8 vdat = *(const bf16x8*)(slice + rl * SLICE_LD + lm * 8);
            *(bf16x8*)(xp1 + (size_t)row * HD + lm * 8) = vdat;
        }
    }
}

// ---------------------------------------------------------------------------
// K2: gather layer 1, one wave per node, with DEG-0 FAST PATH (~67% of
// nodes). Deg>0: lane-parallel weight precompute + 2-way unrolled gather.
// ---------------------------------------------------------------------------
__global__ __launch_bounds__(256) void k2_gather(
    const unsigned short* __restrict__ xp1, const float* __restrict__ denom1,
    const float* __restrict__ es1, const float* __restrict__ ed1,
    const int* __restrict__ deg, const int* __restrict__ adj,
    const float* __restrict__ b1, const float* __restrict__ W2,
    float* __restrict__ xp2)
{
    const int wid = threadIdx.x >> 6;
    const int lane = threadIdx.x & 63;
    const int i = blockIdx.x * 4 + wid;
    if (i >= N_NODES) return;

    const int dcount = min(deg[i], CAP);

    const unsigned pself = ((const unsigned*)(xp1 + (size_t)i * HD))[lane];
    float a0 = bf2f(pself & 0xFFFFu);
    float a1 = bf2f(pself >> 16);

    if (dcount > 0) {
        const float wself = denom1[i];
        const float edv   = ed1[i];
        const int* arow = adj + (size_t)i * CAP;

        // parallel neighbor metadata (one gather + exp per lane)
        int nidx = 0; float nw = 0.f;
        if (lane < dcount) {
            nidx = arow[lane];
            const float lgt = es1[nidx] + edv;
            nw = __expf(lgt > 0.f ? lgt : SLOPE * lgt);
        }
        float dsum = nw;
        #pragma unroll
        for (int m = 32; m > 0; m >>= 1) dsum += __shfl_xor(dsum, m, 64);
        const float inv = 1.f / (wself + dsum);

        a0 *= wself;
        a1 *= wself;

        int j = 0;
        for (; j + 2 <= dcount; j += 2) {
            const int   s0 = __shfl(nidx, j, 64);
            const int   s1 = __shfl(nidx, j + 1, 64);
            const float w0 = __shfl(nw, j, 64);
            const float w1 = __shfl(nw, j + 1, 64);
            const unsigned p0 = ((const unsigned*)(xp1 + (size_t)s0 * HD))[lane];
            const unsigned p1 = ((const unsigned*)(xp1 + (size_t)s1 * HD))[lane];
            a0 += w0 * bf2f(p0 & 0xFFFFu) + w1 * bf2f(p1 & 0xFFFFu);
            a1 += w0 * bf2f(p0 >> 16)     + w1 * bf2f(p1 >> 16);
        }
        if (j < dcount) {
            const int   s0 = __shfl(nidx, j, 64);
            const float w0 = __shfl(nw, j, 64);
            const unsigned p0 = ((const unsigned*)(xp1 + (size_t)s0 * HD))[lane];
            a0 += w0 * bf2f(p0 & 0xFFFFu);
            a1 += w0 * bf2f(p0 >> 16);
        }
        a0 *= inv;
        a1 *= inv;
    }
    // deg==0: denom == wself, numerator == wself * x  ->  a = x (already)

    const float o0 = fmaxf(a0 + b1[2 * lane],     0.f);
    const float o1 = fmaxf(a1 + b1[2 * lane + 1], 0.f);

    float part = o0 * W2[2 * lane] + o1 * W2[2 * lane + 1];
    #pragma unroll
    for (int off = 32; off > 0; off >>= 1) part += __shfl_down(part, off, 64);
    if (lane == 0) xp2[i] = part;
}

// ---------------------------------------------------------------------------
// K3: layer 2 over scalars (one thread per node) with deg-0 fast path
// (out = xi + b2); deg>0: 2-way unrolled int2 adjacency + independent exps.
// ---------------------------------------------------------------------------
__global__ __launch_bounds__(256) void k3_final(
    const float* __restrict__ xp2, const int* __restrict__ deg,
    const int* __restrict__ adj,
    const float* __restrict__ a_src2, const float* __restrict__ a_dst2,
    const float* __restrict__ b2, float* __restrict__ out)
{
    const int i = blockIdx.x * 256 + threadIdx.x;
    if (i >= N_NODES) return;

    const float xi = xp2[i];
    const int dcount = min(deg[i], CAP);
    if (dcount == 0) {                       // denom=wself, num=wself*xi
        out[i] = xi + b2[0];
        return;
    }

    const float as = a_src2[0], ad = a_dst2[0];
    const float adxi = ad * xi;
    const float s0 = (as + ad) * xi;
    const float l0 = s0 > 0.f ? s0 : SLOPE * s0;
    const float wself = __expf(l0);

    float denom = wself, num = wself * xi;
    const int* arow = adj + (size_t)i * CAP;

    int j = 0;
    for (; j + 2 <= dcount; j += 2) {
        const int2 ss = *(const int2*)(arow + j);
        const float x0 = xp2[ss.x];
        const float x1 = xp2[ss.y];
        float l0e = as * x0 + adxi; l0e = l0e > 0.f ? l0e : SLOPE * l0e;
        float l1e = as * x1 + adxi; l1e = l1e > 0.f ? l1e : SLOPE * l1e;
        const float w0 = __expf(l0e);
        const float w1 = __expf(l1e);
        denom += w0 + w1;
        num   += w0 * x0 + w1 * x1;
    }
    if (j < dcount) {
        const float x0 = xp2[arow[j]];
        float l0e = as * x0 + adxi; l0e = l0e > 0.f ? l0e : SLOPE * l0e;
        const float w0 = __expf(l0e);
        denom += w0;
        num   += w0 * x0;
    }
    out[i] = num / denom + b2[0];
}

extern "C" void kernel_launch(void* const* d_in, const int* in_sizes, int n_in,
                              void* d_out, int out_size, void* d_ws, size_t ws_size,
                              hipStream_t stream)
{
    const int* h   = (const int*)d_in[0];
    const int* ei  = (const int*)d_in[1];
    const int* nt  = (const int*)d_in[2];
    const float* emb    = (const float*)d_in[3];
    const float* W1     = (const float*)d_in[4];
    const float* a_src1 = (const float*)d_in[5];
    const float* a_dst1 = (const float*)d_in[6];
    const float* b1     = (const float*)d_in[7];
    const float* W2     = (const float*)d_in[8];
    const float* a_src2 = (const float*)d_in[9];
    const float* a_dst2 = (const float*)d_in[10];
    const float* b2     = (const float*)d_in[11];
    float* out = (float*)d_out;

    char* ws = (char*)d_ws;
    size_t off = 0;
    unsigned short* xp1 = (unsigned short*)(ws + off); off += (size_t)N_NODES * HD * sizeof(unsigned short);
    float* es1    = (float*)(ws + off); off += (size_t)N_NODES * sizeof(float);
    float* ed1    = (float*)(ws + off); off += (size_t)N_NODES * sizeof(float);
    float* denom1 = (float*)(ws + off); off += (size_t)N_NODES * sizeof(float);
    float* xp2    = (float*)(ws + off); off += (size_t)N_NODES * sizeof(float);
    int*   deg    = (int*)(ws + off);   off += (size_t)N_NODES * sizeof(int);
    unsigned* umask = (unsigned*)(ws + off); off += 3200 * sizeof(unsigned);
    unsigned short* W1bfT = (unsigned short*)(ws + off); off += (size_t)HD * HD * sizeof(unsigned short);
    off = (off + 255) & ~(size_t)255;
    int*   adj    = (int*)(ws + off);   off += (size_t)N_NODES * CAP * sizeof(int);

    k0_zero<<<NBLK, 256, 0, stream>>>(nt, W1, deg, umask, W1bfT);
    k1a_edge<<<EB3, 512, 0, stream>>>(ei, umask, deg, adj);
    k1b_gemm<<<GB, 512, 0, stream>>>(
        h, emb, W1bfT, a_src1, a_dst1, xp1, es1, ed1, denom1);
    k2_gather<<<(N_NODES + 3) / 4, 256, 0, stream>>>(
        xp1, denom1, es1, ed1, deg, adj, b1, W2, xp2);
    k3_final<<<NBLK, 256, 0, stream>>>(
        xp2, deg, adj, a_src2, a_dst2, b2, out);
}